// Round 1
// baseline (1229.040 us; speedup 1.0000x reference)
//
#include <hip/hip_runtime.h>
#include <math.h>

// Shapes (fixed): BS=128, L=256, D=512, H=2, DK=256
// Only positions 0..255 of ga_jw are ever gathered (idx = lengths-1 < 256),
// so conv branches / BN2 / BN3 / f2 / f3 are dead code. Attention output,
// BN1, MLP, l2norm needed only at the gathered row per batch sample.

__device__ __forceinline__ float sigmoidf_(float x) { return 1.f / (1.f + expf(-x)); }

// C[m,n] = f(sum_k A[m,k]*B[n,k] + bias[n])  (torch Linear: B row-major (out,in))
// MODE 0: f = identity
// MODE 1: f = sigmoid(.) * E[m,n]   (kg = sigmoid(lin) * K), may be in-place (C==E)
// MODE 2: f = (.) * E[m,n]          (G = (lin) * Fk), may be in-place
template<int MODE>
__global__ __launch_bounds__(256)
void gemm_bt(const float* __restrict__ A, int lda, int zA,
             const float* __restrict__ B, int ldb,
             const float* __restrict__ bias,
             const float* __restrict__ E,
             float* __restrict__ C, int ldc, int zC,
             int K)
{
    __shared__ float As[16][132];
    __shared__ float Bs[16][132];
    const int z = blockIdx.z;
    A += (size_t)z * zA;
    C += (size_t)z * zC;
    const float* Ep = (MODE != 0) ? (E + (size_t)z * zC) : nullptr;
    const int bm = blockIdx.y * 128;
    const int bn = blockIdx.x * 128;
    const int tid = threadIdx.x;
    const int tx = tid & 15, ty = tid >> 4;

    float acc[8][8];
#pragma unroll
    for (int i = 0; i < 8; ++i)
#pragma unroll
        for (int j = 0; j < 8; ++j) acc[i][j] = 0.f;

    for (int k0 = 0; k0 < K; k0 += 16) {
#pragma unroll
        for (int i = 0; i < 2; ++i) {
            int Lidx = tid + i * 256;
            int row = Lidx >> 2;
            int c4 = (Lidx & 3) << 2;
            float4 a = *(const float4*)(A + (size_t)(bm + row) * lda + k0 + c4);
            As[c4 + 0][row] = a.x; As[c4 + 1][row] = a.y;
            As[c4 + 2][row] = a.z; As[c4 + 3][row] = a.w;
            float4 b = *(const float4*)(B + (size_t)(bn + row) * ldb + k0 + c4);
            Bs[c4 + 0][row] = b.x; Bs[c4 + 1][row] = b.y;
            Bs[c4 + 2][row] = b.z; Bs[c4 + 3][row] = b.w;
        }
        __syncthreads();
#pragma unroll
        for (int k = 0; k < 16; ++k) {
            float ar[8], br[8];
#pragma unroll
            for (int i = 0; i < 8; ++i) ar[i] = As[k][ty * 8 + i];
#pragma unroll
            for (int j = 0; j < 8; ++j) br[j] = Bs[k][tx * 8 + j];
#pragma unroll
            for (int i = 0; i < 8; ++i)
#pragma unroll
                for (int j = 0; j < 8; ++j)
                    acc[i][j] = fmaf(ar[i], br[j], acc[i][j]);
        }
        __syncthreads();
    }

#pragma unroll
    for (int i = 0; i < 8; ++i) {
        int m = bm + ty * 8 + i;
#pragma unroll
        for (int j = 0; j < 8; ++j) {
            int n = bn + tx * 8 + j;
            float v = acc[i][j] + bias[n];
            size_t off = (size_t)m * ldc + n;
            if (MODE == 1) v = sigmoidf_(v) * Ep[off];
            if (MODE == 2) v = v * Ep[off];
            C[off] = v;
        }
    }
}

// One block per batch sample: gathered-row attention + BN1 + residual MLP + l2norm.
__global__ __launch_bounds__(256)
void tail_kernel(const float* __restrict__ cap, const int* __restrict__ lengths,
                 const float* __restrict__ Q, const float* __restrict__ G,
                 const float* __restrict__ KG, const float* __restrict__ V,
                 const float* __restrict__ Wfg, const float* __restrict__ bfg,
                 const float* __restrict__ g1, const float* __restrict__ b1,
                 const float* __restrict__ m1, const float* __restrict__ v1,
                 const float* __restrict__ Wm1, const float* __restrict__ bm1,
                 const float* __restrict__ Wm2, const float* __restrict__ bm2,
                 float* __restrict__ out)
{
    __shared__ float gRow[512], qg[512], sc[512], red[512], xga[512], hid[1024];
    const int b = blockIdx.x;
    const int t = threadIdx.x;
    int r = lengths[b] - 1;
    if (r < 0) r = 0;
    if (r > 255) r = 255;
    const size_t base = ((size_t)b * 256 + r) * 512;

    gRow[t] = G[base + t];
    gRow[t + 256] = G[base + 256 + t];
    __syncthreads();

    // qg = Q[row] * sigmoid(Wfg[:256] @ G_head + bfg[:256])
#pragma unroll
    for (int i = 0; i < 2; ++i) {
        int o = t + i * 256;
        int h = o >> 8, d = o & 255;
        const float4* w4 = (const float4*)(Wfg + (size_t)d * 256);
        const float* gh = gRow + h * 256;
        float acc = 0.f;
        for (int k4 = 0; k4 < 64; ++k4) {
            float4 w = w4[k4];
            acc += w.x * gh[k4 * 4 + 0] + w.y * gh[k4 * 4 + 1]
                 + w.z * gh[k4 * 4 + 2] + w.w * gh[k4 * 4 + 3];
        }
        acc += bfg[d];
        float m = 1.f / (1.f + expf(-acc));
        qg[o] = Q[base + o] * m;
    }
    __syncthreads();

    // scores[h][j] = floor(qg_h . kg[b,j,h,:] / 16)
#pragma unroll
    for (int i = 0; i < 2; ++i) {
        int o = t + i * 256;
        int h = o >> 8, j = o & 255;
        const float4* kg4 = (const float4*)(KG + ((size_t)(b * 256 + j)) * 512 + h * 256);
        const float* qh = qg + h * 256;
        float s = 0.f;
        for (int d4 = 0; d4 < 64; ++d4) {
            float4 kv = kg4[d4];
            s += kv.x * qh[d4 * 4 + 0] + kv.y * qh[d4 * 4 + 1]
               + kv.z * qh[d4 * 4 + 2] + kv.w * qh[d4 * 4 + 3];
        }
        sc[o] = floorf(s * 0.0625f);
    }
    __syncthreads();

    // softmax per head (length 256 each)
    red[t] = sc[t]; red[t + 256] = sc[t + 256];
    __syncthreads();
    for (int s = 128; s > 0; s >>= 1) {
        if (t < s) {
            red[t] = fmaxf(red[t], red[t + s]);
            red[256 + t] = fmaxf(red[256 + t], red[256 + t + s]);
        }
        __syncthreads();
    }
    const float mx0 = red[0], mx1 = red[256];
    __syncthreads();
    float e0 = expf(sc[t] - mx0);
    float e1 = expf(sc[t + 256] - mx1);
    sc[t] = e0; sc[t + 256] = e1;
    red[t] = e0; red[t + 256] = e1;
    __syncthreads();
    for (int s = 128; s > 0; s >>= 1) {
        if (t < s) { red[t] += red[t + s]; red[256 + t] += red[256 + t + s]; }
        __syncthreads();
    }
    const float inv0 = 1.f / red[0];
    const float inv1 = 1.f / red[256];

    // x = p @ V (per head), then ga = cap + BN1(x)
    {
        float x0 = 0.f, x1 = 0.f;
        for (int j = 0; j < 256; ++j) {
            const float* vr = V + ((size_t)(b * 256 + j)) * 512;
            x0 += sc[j] * vr[t];
            x1 += sc[256 + j] * vr[256 + t];
        }
        x0 *= inv0; x1 *= inv1;
        int c0 = t, c1 = t + 256;
        float s0 = g1[c0] / sqrtf(v1[c0] + 1e-5f);
        float s1 = g1[c1] / sqrtf(v1[c1] + 1e-5f);
        xga[c0] = cap[base + c0] + (x0 - m1[c0]) * s0 + b1[c0];
        xga[c1] = cap[base + c1] + (x1 - m1[c1]) * s1 + b1[c1];
    }
    __syncthreads();

    // hid = relu(ga @ Wm1^T + bm1)
#pragma unroll
    for (int i = 0; i < 4; ++i) {
        int j = t + i * 256;
        const float4* w4 = (const float4*)(Wm1 + (size_t)j * 512);
        float a = 0.f;
        for (int c4 = 0; c4 < 128; ++c4) {
            float4 w = w4[c4];
            a += w.x * xga[c4 * 4 + 0] + w.y * xga[c4 * 4 + 1]
               + w.z * xga[c4 * 4 + 2] + w.w * xga[c4 * 4 + 3];
        }
        a += bm1[j];
        hid[j] = fmaxf(a, 0.f);
    }
    __syncthreads();

    // tex = hid @ Wm2^T + bm2 + ga ; out = tex / (||tex|| + 1e-8)
    float tex0, tex1;
    {
        const float4* w4 = (const float4*)(Wm2 + (size_t)t * 1024);
        float a = 0.f;
        for (int j4 = 0; j4 < 256; ++j4) {
            float4 w = w4[j4];
            a += w.x * hid[j4 * 4 + 0] + w.y * hid[j4 * 4 + 1]
               + w.z * hid[j4 * 4 + 2] + w.w * hid[j4 * 4 + 3];
        }
        tex0 = a + bm2[t] + xga[t];
    }
    {
        const float4* w4 = (const float4*)(Wm2 + (size_t)(t + 256) * 1024);
        float a = 0.f;
        for (int j4 = 0; j4 < 256; ++j4) {
            float4 w = w4[j4];
            a += w.x * hid[j4 * 4 + 0] + w.y * hid[j4 * 4 + 1]
               + w.z * hid[j4 * 4 + 2] + w.w * hid[j4 * 4 + 3];
        }
        tex1 = a + bm2[t + 256] + xga[t + 256];
    }
    red[t] = tex0 * tex0 + tex1 * tex1;
    __syncthreads();
    for (int s = 128; s > 0; s >>= 1) {
        if (t < s) red[t] += red[t + s];
        __syncthreads();
    }
    const float invn = 1.f / (sqrtf(red[0]) + 1e-8f);
    out[(size_t)b * 512 + t] = tex0 * invn;
    out[(size_t)b * 512 + t + 256] = tex1 * invn;
}

extern "C" void kernel_launch(void* const* d_in, const int* in_sizes, int n_in,
                              void* d_out, int out_size, void* d_ws, size_t ws_size,
                              hipStream_t stream)
{
    const float* cap = (const float*)d_in[0];
    const int*   lengths = (const int*)d_in[1];
    const float* Wq  = (const float*)d_in[2];
    const float* Wk  = (const float*)d_in[3];
    const float* Wv  = (const float*)d_in[4];
    const float* bq  = (const float*)d_in[5];
    const float* bk  = (const float*)d_in[6];
    const float* bv  = (const float*)d_in[7];
    const float* Wfq = (const float*)d_in[8];
    const float* bfq = (const float*)d_in[9];
    const float* Wfk = (const float*)d_in[10];
    const float* bfk = (const float*)d_in[11];
    const float* Wfg = (const float*)d_in[12];
    const float* bfg = (const float*)d_in[13];
    const float* g1  = (const float*)d_in[14];
    const float* b1  = (const float*)d_in[15];
    const float* m1  = (const float*)d_in[16];
    const float* v1  = (const float*)d_in[17];
    // d_in[18..25]: bn2/bn3 params (dead), d_in[26..29]: conv weights (dead)
    const float* Wm1 = (const float*)d_in[30];
    const float* bm1 = (const float*)d_in[31];
    const float* Wm2 = (const float*)d_in[32];
    const float* bm2 = (const float*)d_in[33];
    float* out = (float*)d_out;

    const size_t BUF = 128ull * 256 * 512;  // 16.78M floats = 64 MiB
    float* Qb = (float*)d_ws;
    float* Kb = Qb + BUF;
    float* Vb = Kb + BUF;
    float* Fk = Vb + BUF;   // total 256 MiB of workspace

    dim3 blk(256);
    // Q, K, V projections: [32768,512] @ [512,512]^T
    gemm_bt<0><<<dim3(4, 256, 1), blk, 0, stream>>>(cap, 512, 0, Wq, 512, bq, nullptr, Qb, 512, 0, 512);
    gemm_bt<0><<<dim3(4, 256, 1), blk, 0, stream>>>(cap, 512, 0, Wk, 512, bk, nullptr, Kb, 512, 0, 512);
    gemm_bt<0><<<dim3(4, 256, 1), blk, 0, stream>>>(cap, 512, 0, Wv, 512, bv, nullptr, Vb, 512, 0, 512);
    // Fk = K_h @ Wfk^T + bfk   (per head via z)
    gemm_bt<0><<<dim3(2, 256, 2), blk, 0, stream>>>(Kb, 512, 256, Wfk, 256, bfk, nullptr, Fk, 512, 256, 256);
    // G = (Q_h @ Wfq^T + bfq) * Fk   (in-place into Fk)
    gemm_bt<2><<<dim3(2, 256, 2), blk, 0, stream>>>(Qb, 512, 256, Wfq, 256, bfq, Fk, Fk, 512, 256, 256);
    // kg = sigmoid(G_h @ Wfg[256:]^T + bfg[256:]) * K   (in-place into Kb)
    gemm_bt<1><<<dim3(2, 256, 2), blk, 0, stream>>>(Fk, 512, 256, Wfg + 256 * 256, 256, bfg + 256, Kb, Kb, 512, 256, 256);
    // gathered-row attention + BN1 + MLP + l2norm
    tail_kernel<<<dim3(128), blk, 0, stream>>>(cap, lengths, Qb, Fk, Kb, Vb, Wfg, bfg,
                                               g1, b1, m1, v1, Wm1, bm1, Wm2, bm2, out);
}

// Round 2
// 470.014 us; speedup vs baseline: 2.6149x; 2.6149x over previous
//
#include <hip/hip_runtime.h>
#include <math.h>

// BS=128, L=256, D=512, H=2, DK=256.
// Conv branches dead (gather idx < 256). Split-bf16 (hi/lo) MFMA GEMMs for the
// score-critical chain; plain bf16 for V; fp32 vector tail on 128 rows.

typedef short bf16x8 __attribute__((ext_vector_type(8)));
typedef float f32x4 __attribute__((ext_vector_type(4)));
typedef short short4v __attribute__((ext_vector_type(4)));

__device__ __forceinline__ short f2bf(float x) {
    union { float f; unsigned u; } c; c.f = x;
    unsigned r = c.u + 0x7FFFu + ((c.u >> 16) & 1u);
    return (short)(r >> 16);
}
__device__ __forceinline__ float bf2f(short h) {
    union { float f; unsigned u; } c; c.u = ((unsigned)(unsigned short)h) << 16;
    return c.f;
}
__device__ __forceinline__ void glds16(const void* g, void* l) {
    __builtin_amdgcn_global_load_lds(
        (const __attribute__((address_space(1))) void*)g,
        (__attribute__((address_space(3))) void*)l, 16, 0, 0);
}

// ---------------- split fp32 -> bf16 hi/lo ----------------
struct SplitArgs {
    const float* src[7];
    short* hi[7];
    short* lo[7];
    int n4[7];
};
__global__ __launch_bounds__(256) void split_multi(SplitArgs a)
{
    const int j = blockIdx.y;
    const float4* s = (const float4*)a.src[j];
    short* hi = a.hi[j];
    short* lo = a.lo[j];
    const int n4 = a.n4[j];
    for (int i = blockIdx.x * 256 + threadIdx.x; i < n4; i += gridDim.x * 256) {
        float4 x = s[i];
        short4v h, l;
        h.x = f2bf(x.x); l.x = f2bf(x.x - bf2f(h.x));
        h.y = f2bf(x.y); l.y = f2bf(x.y - bf2f(h.y));
        h.z = f2bf(x.z); l.z = f2bf(x.z - bf2f(h.z));
        h.w = f2bf(x.w); l.w = f2bf(x.w - bf2f(h.w));
        *(short4v*)&hi[i * 4] = h;
        *(short4v*)&lo[i * 4] = l;
    }
}

// ---------------- MFMA GEMM, C = A * B^T (+epilogues) ----------------
// NSPLIT=3: virtual K-loop hi*hi, lo*hi, hi*lo.  NSPLIT=1: plain bf16.
// MODE 1: split-write hi/lo of (acc+bias)                      [Q, K]
// MODE 2: bf16 write of (acc+bias)                             [V]
// MODE 3: split-write of (acc+bias)*(acc2+bias2), dual K-loop  [G]
// MODE 4: fp32 write of sigmoid(acc+bias)*(E1+E2)              [kg]
template<int NSPLIT>
__device__ __forceinline__ void kloop(const short* Ahi, const short* Alo, int lda,
                                      const short* Bhi, const short* Blo, int ldb,
                                      int K, int bm, int bn,
                                      short* As, short* Bs, int tid, f32x4 acc[4][4])
{
    const int lane = tid & 63;
    const int wv = tid >> 6;
    const int wr = wv >> 1, wc = wv & 1;
    const int fr = lane & 15, kc = lane >> 4;
    const int c0 = tid, c1 = tid + 256;
    const int r0 = c0 >> 2, e0 = (c0 & 3) * 8;
    const int r1 = c1 >> 2, e1 = (c1 & 3) * 8;
    const int NK = (K / 32) * NSPLIT;
    for (int s = 0; s < NK; ++s) {
        const int kv = s * 32;
        const short* pa;
        const short* pb;
        if (NSPLIT == 1) { pa = Ahi + kv; pb = Bhi + kv; }
        else if (kv < K) { pa = Ahi + kv; pb = Bhi + kv; }
        else if (kv < 2 * K) { pa = Alo + (kv - K); pb = Bhi + (kv - K); }
        else { pa = Ahi + (kv - 2 * K); pb = Blo + (kv - 2 * K); }
        glds16(pa + (size_t)(bm + r0) * lda + e0, As + c0 * 8);
        glds16(pa + (size_t)(bm + r1) * lda + e1, As + c1 * 8);
        glds16(pb + (size_t)(bn + r0) * ldb + e0, Bs + c0 * 8);
        glds16(pb + (size_t)(bn + r1) * ldb + e1, Bs + c1 * 8);
        __syncthreads();
        bf16x8 af[4], bfr[4];
#pragma unroll
        for (int mi = 0; mi < 4; ++mi)
            af[mi] = *(const bf16x8*)&As[(wr * 64 + mi * 16 + fr) * 32 + kc * 8];
#pragma unroll
        for (int ni = 0; ni < 4; ++ni)
            bfr[ni] = *(const bf16x8*)&Bs[(wc * 64 + ni * 16 + fr) * 32 + kc * 8];
#pragma unroll
        for (int mi = 0; mi < 4; ++mi)
#pragma unroll
            for (int ni = 0; ni < 4; ++ni)
                acc[mi][ni] = __builtin_amdgcn_mfma_f32_16x16x32_bf16(af[mi], bfr[ni], acc[mi][ni], 0, 0, 0);
        __syncthreads();
    }
}

template<int MODE, int NSPLIT>
__global__ __launch_bounds__(256, 2)
void gemm_mfma(const short* __restrict__ Ahi, const short* __restrict__ Alo, int lda,
               const short* __restrict__ Bhi, const short* __restrict__ Blo, int ldb,
               const float* __restrict__ bias,
               const short* __restrict__ A2hi, const short* __restrict__ A2lo,
               const short* __restrict__ B2hi, const short* __restrict__ B2lo,
               const float* __restrict__ bias2,
               const short* __restrict__ E1, const short* __restrict__ E2,
               void* __restrict__ C0, void* __restrict__ C1,
               int ldc, int K, int zColA, int zColC)
{
    __shared__ short As[128 * 32];
    __shared__ short Bs[128 * 32];
    const int tid = threadIdx.x;
    const int bm = blockIdx.y * 128;
    const int bn = blockIdx.x * 128;
    const size_t zA = (size_t)blockIdx.z * zColA;
    const size_t zC = (size_t)blockIdx.z * zColC;
    Ahi += zA;
    if (NSPLIT == 3) Alo += zA;

    f32x4 acc[4][4];
#pragma unroll
    for (int i = 0; i < 4; ++i)
#pragma unroll
        for (int j = 0; j < 4; ++j) acc[i][j] = (f32x4){0.f, 0.f, 0.f, 0.f};
    kloop<NSPLIT>(Ahi, Alo, lda, Bhi, Blo, ldb, K, bm, bn, As, Bs, tid, acc);

    f32x4 acc2[4][4];
    if (MODE == 3) {
#pragma unroll
        for (int i = 0; i < 4; ++i)
#pragma unroll
            for (int j = 0; j < 4; ++j) acc2[i][j] = (f32x4){0.f, 0.f, 0.f, 0.f};
        kloop<NSPLIT>(A2hi + zA, A2lo + zA, lda, B2hi, B2lo, ldb, K, bm, bn, As, Bs, tid, acc2);
    }

    const int lane = tid & 63;
    const int wv = tid >> 6;
    const int wr = wv >> 1, wc = wv & 1;
    const int fr = lane & 15, kc = lane >> 4;
#pragma unroll
    for (int mi = 0; mi < 4; ++mi) {
#pragma unroll
        for (int ni = 0; ni < 4; ++ni) {
#pragma unroll
            for (int r = 0; r < 4; ++r) {
                const int row = bm + wr * 64 + mi * 16 + kc * 4 + r;
                const int col = bn + wc * 64 + ni * 16 + fr;
                const size_t off = (size_t)row * ldc + col + zC;
                float v = acc[mi][ni][r] + bias[col];
                if (MODE == 1) {
                    short h = f2bf(v);
                    ((short*)C0)[off] = h;
                    ((short*)C1)[off] = f2bf(v - bf2f(h));
                } else if (MODE == 2) {
                    ((short*)C0)[off] = f2bf(v);
                } else if (MODE == 3) {
                    float p = v * (acc2[mi][ni][r] + bias2[col]);
                    short h = f2bf(p);
                    ((short*)C0)[off] = h;
                    ((short*)C1)[off] = f2bf(p - bf2f(h));
                } else if (MODE == 4) {
                    float e = bf2f(E1[off]) + bf2f(E2[off]);
                    ((float*)C0)[off] = e / (1.f + expf(-v));
                }
            }
        }
    }
}

// ---------------- qg = Q[row] * sigmoid(Wfg1 @ G[row] + bfg1), gathered rows ----------------
__global__ __launch_bounds__(256)
void qg_kernel(const short* __restrict__ Qhi, const short* __restrict__ Qlo,
               const short* __restrict__ Ghi, const short* __restrict__ Glo,
               const float* __restrict__ Wfg, const float* __restrict__ bfg,
               const int* __restrict__ lengths, float* __restrict__ qg)
{
    __shared__ float gs[256];
    const int bh = blockIdx.x;
    const int b = bh >> 1, h = bh & 1;
    const int t = threadIdx.x;
    int r = lengths[b] - 1;
    if (r < 0) r = 0;
    if (r > 255) r = 255;
    const size_t base = ((size_t)b * 256 + r) * 512 + h * 256;
    gs[t] = bf2f(Ghi[base + t]) + bf2f(Glo[base + t]);
    __syncthreads();
    const float4* w4 = (const float4*)(Wfg + (size_t)t * 256);
    float a = 0.f;
    for (int k4 = 0; k4 < 64; ++k4) {
        float4 w = w4[k4];
        a += w.x * gs[k4 * 4 + 0] + w.y * gs[k4 * 4 + 1]
           + w.z * gs[k4 * 4 + 2] + w.w * gs[k4 * 4 + 3];
    }
    a += bfg[t];
    const float qv = bf2f(Qhi[base + t]) + bf2f(Qlo[base + t]);
    qg[b * 512 + h * 256 + t] = qv / (1.f + expf(-a));
}

// ---------------- per-sample attention + BN1 + residual ----------------
__global__ __launch_bounds__(256)
void attn_tail(const float* __restrict__ qg, const float* __restrict__ kg,
               const short* __restrict__ Vbf, const float* __restrict__ cap,
               const int* __restrict__ lengths,
               const float* __restrict__ g1, const float* __restrict__ b1,
               const float* __restrict__ m1, const float* __restrict__ v1,
               float* __restrict__ xga)
{
    __shared__ float qs[512], sc[512], red[512];
    const int b = blockIdx.x;
    const int t = threadIdx.x;
    int r = lengths[b] - 1;
    if (r < 0) r = 0;
    if (r > 255) r = 255;
    const size_t base = ((size_t)b * 256 + r) * 512;

    qs[t] = qg[b * 512 + t];
    qs[t + 256] = qg[b * 512 + 256 + t];
    __syncthreads();

#pragma unroll
    for (int i = 0; i < 2; ++i) {
        const int o = t + i * 256;
        const int h = o >> 8, j = o & 255;
        const float4* kg4 = (const float4*)(kg + ((size_t)(b * 256 + j)) * 512 + h * 256);
        const float* qh = qs + h * 256;
        float s = 0.f;
        for (int d4 = 0; d4 < 64; ++d4) {
            float4 kv = kg4[d4];
            s += kv.x * qh[d4 * 4 + 0] + kv.y * qh[d4 * 4 + 1]
               + kv.z * qh[d4 * 4 + 2] + kv.w * qh[d4 * 4 + 3];
        }
        sc[o] = floorf(s * 0.0625f);
    }
    __syncthreads();

    red[t] = sc[t]; red[t + 256] = sc[t + 256];
    __syncthreads();
    for (int s = 128; s > 0; s >>= 1) {
        if (t < s) {
            red[t] = fmaxf(red[t], red[t + s]);
            red[256 + t] = fmaxf(red[256 + t], red[256 + t + s]);
        }
        __syncthreads();
    }
    const float mx0 = red[0], mx1 = red[256];
    __syncthreads();
    const float e0 = expf(sc[t] - mx0);
    const float e1 = expf(sc[t + 256] - mx1);
    sc[t] = e0; sc[t + 256] = e1;
    red[t] = e0; red[t + 256] = e1;
    __syncthreads();
    for (int s = 128; s > 0; s >>= 1) {
        if (t < s) { red[t] += red[t + s]; red[256 + t] += red[256 + t + s]; }
        __syncthreads();
    }
    const float inv0 = 1.f / red[0];
    const float inv1 = 1.f / red[256];

    float x0 = 0.f, x1 = 0.f;
    for (int j = 0; j < 256; ++j) {
        const short* vr = Vbf + ((size_t)(b * 256 + j)) * 512;
        x0 += sc[j] * bf2f(vr[t]);
        x1 += sc[256 + j] * bf2f(vr[256 + t]);
    }
    x0 *= inv0; x1 *= inv1;
    const int c0 = t, c1 = t + 256;
    const float s0 = g1[c0] / sqrtf(v1[c0] + 1e-5f);
    const float s1 = g1[c1] / sqrtf(v1[c1] + 1e-5f);
    xga[b * 512 + c0] = cap[base + c0] + (x0 - m1[c0]) * s0 + b1[c0];
    xga[b * 512 + c1] = cap[base + c1] + (x1 - m1[c1]) * s1 + b1[c1];
}

// ---------------- MLP strip GEMMs (weights read once) ----------------
__global__ __launch_bounds__(256)
void mlp1(const float* __restrict__ xga, const float* __restrict__ W,
          const float* __restrict__ bias, float* __restrict__ hid)
{
    __shared__ float xs[16 * 512];
    const int r0 = blockIdx.y * 16;
    const int c0 = blockIdx.x * 64;
    for (int i = threadIdx.x; i < 2048; i += 256)
        ((float4*)xs)[i] = ((const float4*)(xga + (size_t)r0 * 512))[i];
    __syncthreads();
    const int col = c0 + (threadIdx.x & 63);
    const int rg = (threadIdx.x >> 6) * 4;
    float acc[4] = {0.f, 0.f, 0.f, 0.f};
    const float4* w4 = (const float4*)(W + (size_t)col * 512);
    for (int k4 = 0; k4 < 128; ++k4) {
        float4 w = w4[k4];
#pragma unroll
        for (int rr = 0; rr < 4; ++rr) {
            float4 x = *(const float4*)&xs[(rg + rr) * 512 + k4 * 4];
            acc[rr] += w.x * x.x + w.y * x.y + w.z * x.z + w.w * x.w;
        }
    }
    const float bb = bias[col];
#pragma unroll
    for (int rr = 0; rr < 4; ++rr)
        hid[(size_t)(r0 + rg + rr) * 1024 + col] = fmaxf(acc[rr] + bb, 0.f);
}

__global__ __launch_bounds__(256)
void mlp2(const float* __restrict__ hid, const float* __restrict__ W,
          const float* __restrict__ bias, const float* __restrict__ xga,
          float* __restrict__ tex)
{
    __shared__ float xs[16 * 1024];
    const int r0 = blockIdx.y * 16;
    const int c0 = blockIdx.x * 64;
    for (int i = threadIdx.x; i < 4096; i += 256)
        ((float4*)xs)[i] = ((const float4*)(hid + (size_t)r0 * 1024))[i];
    __syncthreads();
    const int col = c0 + (threadIdx.x & 63);
    const int rg = (threadIdx.x >> 6) * 4;
    float acc[4] = {0.f, 0.f, 0.f, 0.f};
    const float4* w4 = (const float4*)(W + (size_t)col * 1024);
    for (int k4 = 0; k4 < 256; ++k4) {
        float4 w = w4[k4];
#pragma unroll
        for (int rr = 0; rr < 4; ++rr) {
            float4 x = *(const float4*)&xs[(rg + rr) * 1024 + k4 * 4];
            acc[rr] += w.x * x.x + w.y * x.y + w.z * x.z + w.w * x.w;
        }
    }
    const float bb = bias[col];
#pragma unroll
    for (int rr = 0; rr < 4; ++rr) {
        const int row = r0 + rg + rr;
        tex[(size_t)row * 512 + col] = acc[rr] + bb + xga[(size_t)row * 512 + col];
    }
}

__global__ __launch_bounds__(256)
void norm_out(const float* __restrict__ tex, float* __restrict__ out)
{
    __shared__ float red[256];
    const int b = blockIdx.x;
    const int t = threadIdx.x;
    const float a = tex[b * 512 + t];
    const float c = tex[b * 512 + 256 + t];
    red[t] = a * a + c * c;
    __syncthreads();
    for (int s = 128; s > 0; s >>= 1) {
        if (t < s) red[t] += red[t + s];
        __syncthreads();
    }
    const float inv = 1.f / (sqrtf(red[0]) + 1e-8f);
    out[b * 512 + t] = a * inv;
    out[b * 512 + 256 + t] = c * inv;
}

extern "C" void kernel_launch(void* const* d_in, const int* in_sizes, int n_in,
                              void* d_out, int out_size, void* d_ws, size_t ws_size,
                              hipStream_t stream)
{
    const float* cap = (const float*)d_in[0];
    const int* lengths = (const int*)d_in[1];
    const float* Wq  = (const float*)d_in[2];
    const float* Wk  = (const float*)d_in[3];
    const float* Wv  = (const float*)d_in[4];
    const float* bq  = (const float*)d_in[5];
    const float* bk  = (const float*)d_in[6];
    const float* bv  = (const float*)d_in[7];
    const float* Wfq = (const float*)d_in[8];
    const float* bfq = (const float*)d_in[9];
    const float* Wfk = (const float*)d_in[10];
    const float* bfk = (const float*)d_in[11];
    const float* Wfg = (const float*)d_in[12];
    const float* bfg = (const float*)d_in[13];
    const float* g1  = (const float*)d_in[14];
    const float* b1  = (const float*)d_in[15];
    const float* m1  = (const float*)d_in[16];
    const float* v1  = (const float*)d_in[17];
    const float* Wm1 = (const float*)d_in[30];
    const float* bm1 = (const float*)d_in[31];
    const float* Wm2 = (const float*)d_in[32];
    const float* bm2 = (const float*)d_in[33];
    float* out = (float*)d_out;

    const size_t S = 32768ull * 512;   // 16.78M elements
    const size_t SB = S * 2;           // bytes of one bf16 buffer
    char* w = (char*)d_ws;
    short* capHi = (short*)(w + 0);          // -> Ghi after G gemm
    short* capLo = (short*)(w + SB);         // -> Glo
    short* Qhi   = (short*)(w + 2 * SB);     // -> kg (fp32, spans Qhi+Qlo)
    short* Qlo   = (short*)(w + 3 * SB);
    short* Khi   = (short*)(w + 4 * SB);
    short* Klo   = (short*)(w + 5 * SB);
    short* Vbf   = (short*)(w + 6 * SB);
    char* wp = w + 7 * SB;
    short* WqHi = (short*)wp; wp += 524288;
    short* WqLo = (short*)wp; wp += 524288;
    short* WkHi = (short*)wp; wp += 524288;
    short* WkLo = (short*)wp; wp += 524288;
    short* WvHi = (short*)wp; wp += 524288;
    short* WvLo = (short*)wp; wp += 524288;
    short* WfqHi = (short*)wp; wp += 131072;
    short* WfqLo = (short*)wp; wp += 131072;
    short* WfkHi = (short*)wp; wp += 131072;
    short* WfkLo = (short*)wp; wp += 131072;
    short* Wfg2Hi = (short*)wp; wp += 131072;
    short* Wfg2Lo = (short*)wp; wp += 131072;
    float* qg  = (float*)wp; wp += 262144;
    float* xga = (float*)wp; wp += 262144;
    float* hid = (float*)wp; wp += 524288;
    float* tex = (float*)wp; wp += 262144;
    short* Ghi = capHi;
    short* Glo = capLo;
    float* kg = (float*)Qhi;

    // 1. split conversions
    SplitArgs sa;
    sa.src[0] = cap;  sa.hi[0] = capHi; sa.lo[0] = capLo; sa.n4[0] = (int)(S / 4);
    sa.src[1] = Wq;   sa.hi[1] = WqHi;  sa.lo[1] = WqLo;  sa.n4[1] = 65536;
    sa.src[2] = Wk;   sa.hi[2] = WkHi;  sa.lo[2] = WkLo;  sa.n4[2] = 65536;
    sa.src[3] = Wv;   sa.hi[3] = WvHi;  sa.lo[3] = WvLo;  sa.n4[3] = 65536;
    sa.src[4] = Wfq;  sa.hi[4] = WfqHi; sa.lo[4] = WfqLo; sa.n4[4] = 16384;
    sa.src[5] = Wfk;  sa.hi[5] = WfkHi; sa.lo[5] = WfkLo; sa.n4[5] = 16384;
    sa.src[6] = Wfg + 65536; sa.hi[6] = Wfg2Hi; sa.lo[6] = Wfg2Lo; sa.n4[6] = 16384;
    split_multi<<<dim3(4096, 7), 256, 0, stream>>>(sa);

    // 2-4. Q, K (split), V (plain bf16)
    gemm_mfma<1, 3><<<dim3(4, 256, 1), 256, 0, stream>>>(
        capHi, capLo, 512, WqHi, WqLo, 512, bq,
        nullptr, nullptr, nullptr, nullptr, nullptr, nullptr, nullptr,
        Qhi, Qlo, 512, 512, 0, 0);
    gemm_mfma<1, 3><<<dim3(4, 256, 1), 256, 0, stream>>>(
        capHi, capLo, 512, WkHi, WkLo, 512, bk,
        nullptr, nullptr, nullptr, nullptr, nullptr, nullptr, nullptr,
        Khi, Klo, 512, 512, 0, 0);
    gemm_mfma<2, 1><<<dim3(4, 256, 1), 256, 0, stream>>>(
        capHi, nullptr, 512, WvHi, nullptr, 512, bv,
        nullptr, nullptr, nullptr, nullptr, nullptr, nullptr, nullptr,
        Vbf, nullptr, 512, 512, 0, 0);

    // 5. G = (Q_h Wfq^T + bfq) * (K_h Wfk^T + bfk)  -> overwrites cap region
    gemm_mfma<3, 3><<<dim3(2, 256, 2), 256, 0, stream>>>(
        Qhi, Qlo, 512, WfqHi, WfqLo, 256, bfq,
        Khi, Klo, WfkHi, WfkLo, bfk, nullptr, nullptr,
        Ghi, Glo, 512, 256, 256, 256);

    // 6. qg at gathered rows (must precede kg overwriting Q region)
    qg_kernel<<<dim3(256), 256, 0, stream>>>(Qhi, Qlo, Ghi, Glo, Wfg, bfg, lengths, qg);

    // 7. kg = sigmoid(G_h Wfg2^T + bfg2) * K  -> overwrites Q region (fp32)
    gemm_mfma<4, 3><<<dim3(2, 256, 2), 256, 0, stream>>>(
        Ghi, Glo, 512, Wfg2Hi, Wfg2Lo, 256, bfg + 256,
        nullptr, nullptr, nullptr, nullptr, nullptr, Khi, Klo,
        kg, nullptr, 512, 256, 256, 256);

    // 8-11. attention tail + MLP + norm
    attn_tail<<<dim3(128), 256, 0, stream>>>(qg, kg, Vbf, cap, lengths, g1, b1, m1, v1, xga);
    mlp1<<<dim3(16, 8), 256, 0, stream>>>(xga, Wm1, bm1, hid);
    mlp2<<<dim3(8, 8), 256, 0, stream>>>(hid, Wm2, bm2, xga, tex);
    norm_out<<<dim3(128), 256, 0, stream>>>(tex, out);
}

// Round 3
// 395.058 us; speedup vs baseline: 3.1110x; 1.1897x over previous
//
#include <hip/hip_runtime.h>
#include <math.h>

// BS=128, L=256, D=512, H=2, DK=256.
// Conv branches dead (gather idx < 256). Split-bf16 (hi/lo) MFMA GEMMs, score
// partials fused into the kg GEMM epilogue (kg never materialized).

typedef short bf16x8 __attribute__((ext_vector_type(8)));
typedef float f32x4 __attribute__((ext_vector_type(4)));
typedef short short4v __attribute__((ext_vector_type(4)));

__device__ __forceinline__ short f2bf(float x) {
    union { float f; unsigned u; } c; c.f = x;
    unsigned r = c.u + 0x7FFFu + ((c.u >> 16) & 1u);
    return (short)(r >> 16);
}
__device__ __forceinline__ float bf2f(short h) {
    union { float f; unsigned u; } c; c.u = ((unsigned)(unsigned short)h) << 16;
    return c.f;
}
__device__ __forceinline__ void glds16(const void* g, void* l) {
    __builtin_amdgcn_global_load_lds(
        (const __attribute__((address_space(1))) void*)g,
        (__attribute__((address_space(3))) void*)l, 16, 0, 0);
}

// ---------------- split fp32 -> bf16 hi/lo ----------------
struct SplitArgs {
    const float* src[7];
    short* hi[7];
    short* lo[7];
    int n4[7];
};
__global__ __launch_bounds__(256) void split_multi(SplitArgs a)
{
    const int j = blockIdx.y;
    const float4* s = (const float4*)a.src[j];
    short* hi = a.hi[j];
    short* lo = a.lo[j];
    const int n4 = a.n4[j];
    for (int i = blockIdx.x * 256 + threadIdx.x; i < n4; i += gridDim.x * 256) {
        float4 x = s[i];
        short4v h, l;
        h.x = f2bf(x.x); l.x = f2bf(x.x - bf2f(h.x));
        h.y = f2bf(x.y); l.y = f2bf(x.y - bf2f(h.y));
        h.z = f2bf(x.z); l.z = f2bf(x.z - bf2f(h.z));
        h.w = f2bf(x.w); l.w = f2bf(x.w - bf2f(h.w));
        *(short4v*)&hi[i * 4] = h;
        *(short4v*)&lo[i * 4] = l;
    }
}

// ---------------- chunked split K-loop, 2-phase double buffered ----------------
// LDS slots per phase: [0]=Ahi [4096]=Bhi [8192]=Alo [12288]=Blo (shorts)
template<int NSPLIT>
__device__ __forceinline__ void run_kloop(
    const short* __restrict__ Ahi, const short* __restrict__ Alo, int lda,
    const short* __restrict__ Bhi, const short* __restrict__ Blo, int ldb,
    int K, int bm, int bn, short (*lds)[16384], int tid, f32x4 acc[4][4])
{
    const int lane = tid & 63;
    const int wr = (tid >> 7) & 1;
    const int wc = (tid >> 6) & 1;
    const int fr = lane & 15, kc = lane >> 4;
    const int r0 = tid >> 2;
    const int e0 = (tid & 3) * 8;
    const int NS = K / 32;

    auto stage = [&](int ph, int k0) {
        short* b = lds[ph];
        glds16(Ahi + (size_t)(bm + r0) * lda + k0 + e0,      b + tid * 8);
        glds16(Ahi + (size_t)(bm + r0 + 64) * lda + k0 + e0, b + (tid + 256) * 8);
        glds16(Bhi + (size_t)(bn + r0) * ldb + k0 + e0,      b + 4096 + tid * 8);
        glds16(Bhi + (size_t)(bn + r0 + 64) * ldb + k0 + e0, b + 4096 + (tid + 256) * 8);
        if (NSPLIT == 3) {
            glds16(Alo + (size_t)(bm + r0) * lda + k0 + e0,      b + 8192 + tid * 8);
            glds16(Alo + (size_t)(bm + r0 + 64) * lda + k0 + e0, b + 8192 + (tid + 256) * 8);
            glds16(Blo + (size_t)(bn + r0) * ldb + k0 + e0,      b + 12288 + tid * 8);
            glds16(Blo + (size_t)(bn + r0 + 64) * ldb + k0 + e0, b + 12288 + (tid + 256) * 8);
        }
    };

    stage(0, 0);
    __syncthreads();
    for (int s = 0; s < NS; ++s) {
        if (s + 1 < NS) stage((s + 1) & 1, (s + 1) * 32);
        const short* b = lds[s & 1];
        bf16x8 ah[4], bh[4];
#pragma unroll
        for (int i = 0; i < 4; ++i)
            ah[i] = *(const bf16x8*)&b[(wr * 64 + i * 16 + fr) * 32 + kc * 8];
#pragma unroll
        for (int i = 0; i < 4; ++i)
            bh[i] = *(const bf16x8*)&b[4096 + (wc * 64 + i * 16 + fr) * 32 + kc * 8];
#pragma unroll
        for (int mi = 0; mi < 4; ++mi)
#pragma unroll
            for (int ni = 0; ni < 4; ++ni)
                acc[mi][ni] = __builtin_amdgcn_mfma_f32_16x16x32_bf16(ah[mi], bh[ni], acc[mi][ni], 0, 0, 0);
        if (NSPLIT == 3) {
            bf16x8 al[4], bl[4];
#pragma unroll
            for (int i = 0; i < 4; ++i)
                al[i] = *(const bf16x8*)&b[8192 + (wr * 64 + i * 16 + fr) * 32 + kc * 8];
#pragma unroll
            for (int mi = 0; mi < 4; ++mi)
#pragma unroll
                for (int ni = 0; ni < 4; ++ni)
                    acc[mi][ni] = __builtin_amdgcn_mfma_f32_16x16x32_bf16(al[mi], bh[ni], acc[mi][ni], 0, 0, 0);
#pragma unroll
            for (int i = 0; i < 4; ++i)
                bl[i] = *(const bf16x8*)&b[12288 + (wc * 64 + i * 16 + fr) * 32 + kc * 8];
#pragma unroll
            for (int mi = 0; mi < 4; ++mi)
#pragma unroll
                for (int ni = 0; ni < 4; ++ni)
                    acc[mi][ni] = __builtin_amdgcn_mfma_f32_16x16x32_bf16(ah[mi], bl[ni], acc[mi][ni], 0, 0, 0);
        }
        __syncthreads();
    }
}

// MODE 1: QK fused — split-write (acc + bias[col<512? bq : bk]) into C0/C1 ld 1024
// MODE 2: V — bf16 write of (acc+bias)
// MODE 3: G — split-write of (acc+bias)*(acc2+bias2), dual kloop
// MODE 4: kg+score — no kg write; partial score rows into scorep
template<int MODE, int NSPLIT>
__global__ __launch_bounds__(256, 2)
void gemm_mfma(const short* __restrict__ Ahi, const short* __restrict__ Alo, int lda,
               const short* __restrict__ Bhi, const short* __restrict__ Blo, int ldb,
               const float* __restrict__ bias, const float* __restrict__ bias2,
               const short* __restrict__ A2hi, const short* __restrict__ A2lo, int a2off,
               const short* __restrict__ B2hi, const short* __restrict__ B2lo,
               const short* __restrict__ E1, const short* __restrict__ E2, int ldep, int eoff,
               const float* __restrict__ qg, float* __restrict__ scorep,
               void* __restrict__ C0, void* __restrict__ C1,
               int ldc, int K, int aoff, int coff)
{
    __shared__ short lds[2][16384];
    __shared__ float sp[256];
    const int tid = threadIdx.x;
    const int bm = blockIdx.y * 128;
    const int bn = blockIdx.x * 128;
    const int z = blockIdx.z;

    f32x4 acc[4][4];
#pragma unroll
    for (int i = 0; i < 4; ++i)
#pragma unroll
        for (int j = 0; j < 4; ++j) acc[i][j] = (f32x4){0.f, 0.f, 0.f, 0.f};
    run_kloop<NSPLIT>(Ahi + (size_t)z * aoff, (NSPLIT == 3) ? Alo + (size_t)z * aoff : nullptr,
                      lda, Bhi, Blo, ldb, K, bm, bn, lds, tid, acc);

    f32x4 acc2[4][4];
    if (MODE == 3) {
#pragma unroll
        for (int i = 0; i < 4; ++i)
#pragma unroll
            for (int j = 0; j < 4; ++j) acc2[i][j] = (f32x4){0.f, 0.f, 0.f, 0.f};
        run_kloop<NSPLIT>(A2hi + (size_t)z * a2off, A2lo + (size_t)z * a2off,
                          lda, B2hi, B2lo, ldb, K, bm, bn, lds, tid, acc2);
    }

    const int lane = tid & 63;
    const int wr = (tid >> 7) & 1, wc = (tid >> 6) & 1;
    const int fr = lane & 15, kc = lane >> 4;

    float qgv[4];
    float pt[4][4];
    if (MODE == 4) {
        const int b = bm >> 8;
#pragma unroll
        for (int ni = 0; ni < 4; ++ni)
            qgv[ni] = qg[b * 512 + z * 256 + bn + wc * 64 + ni * 16 + fr];
#pragma unroll
        for (int mi = 0; mi < 4; ++mi)
#pragma unroll
            for (int r = 0; r < 4; ++r) pt[mi][r] = 0.f;
    }

#pragma unroll
    for (int mi = 0; mi < 4; ++mi) {
#pragma unroll
        for (int ni = 0; ni < 4; ++ni) {
#pragma unroll
            for (int r = 0; r < 4; ++r) {
                const int row = bm + wr * 64 + mi * 16 + kc * 4 + r;
                const int col = bn + wc * 64 + ni * 16 + fr;
                float bb = (MODE == 1) ? (col < 512 ? bias[col] : bias2[col - 512]) : bias[col];
                float v = acc[mi][ni][r] + bb;
                if (MODE == 1) {
                    const size_t off = (size_t)row * ldc + col;
                    short h = f2bf(v);
                    ((short*)C0)[off] = h;
                    ((short*)C1)[off] = f2bf(v - bf2f(h));
                } else if (MODE == 2) {
                    ((short*)C0)[(size_t)row * ldc + col] = f2bf(v);
                } else if (MODE == 3) {
                    const size_t off = (size_t)row * ldc + z * coff + col;
                    float p = v * (acc2[mi][ni][r] + bias2[col]);
                    short h = f2bf(p);
                    ((short*)C0)[off] = h;
                    ((short*)C1)[off] = f2bf(p - bf2f(h));
                } else if (MODE == 4) {
                    const size_t eoffs = (size_t)row * ldep + z * eoff + col;
                    float e = bf2f(E1[eoffs]) + bf2f(E2[eoffs]);
                    float kgv = e / (1.f + expf(-v));
                    pt[mi][r] += kgv * qgv[ni];
                }
            }
        }
    }

    if (MODE == 4) {
#pragma unroll
        for (int mi = 0; mi < 4; ++mi) {
#pragma unroll
            for (int r = 0; r < 4; ++r) {
                float p = pt[mi][r];
                p += __shfl_xor(p, 1);
                p += __shfl_xor(p, 2);
                p += __shfl_xor(p, 4);
                p += __shfl_xor(p, 8);
                if (fr == 0) {
                    const int row_local = wr * 64 + mi * 16 + kc * 4 + r;
                    sp[row_local * 2 + wc] = p;
                }
            }
        }
        __syncthreads();
        if (tid < 128) {
            const int row = bm + tid;
            const float s = sp[tid * 2] + sp[tid * 2 + 1];
            const int b = row >> 8, j = row & 255;
            scorep[((size_t)(b * 2 + z) * 256 + j) * 2 + blockIdx.x] = s;
        }
    }
}

// ---------------- qg = Q[row] * sigmoid(Wfg1 @ G[row] + bfg1), gathered rows ----------------
__global__ __launch_bounds__(256)
void qg_kernel(const short* __restrict__ QKhi, const short* __restrict__ QKlo,
               const short* __restrict__ Ghi, const short* __restrict__ Glo,
               const float* __restrict__ Wfg, const float* __restrict__ bfg,
               const int* __restrict__ lengths, float* __restrict__ qg)
{
    __shared__ float gs[256];
    const int bh = blockIdx.x;
    const int b = bh >> 1, h = bh & 1;
    const int t = threadIdx.x;
    int r = lengths[b] - 1;
    if (r < 0) r = 0;
    if (r > 255) r = 255;
    const size_t grow = ((size_t)b * 256 + r) * 512 + h * 256;
    const size_t qrow = ((size_t)b * 256 + r) * 1024 + h * 256;
    gs[t] = bf2f(Ghi[grow + t]) + bf2f(Glo[grow + t]);
    __syncthreads();
    const float4* w4 = (const float4*)(Wfg + (size_t)t * 256);
    float a = 0.f;
    for (int k4 = 0; k4 < 64; ++k4) {
        float4 w = w4[k4];
        a += w.x * gs[k4 * 4 + 0] + w.y * gs[k4 * 4 + 1]
           + w.z * gs[k4 * 4 + 2] + w.w * gs[k4 * 4 + 3];
    }
    a += bfg[t];
    const float qv = bf2f(QKhi[qrow + t]) + bf2f(QKlo[qrow + t]);
    qg[b * 512 + h * 256 + t] = qv / (1.f + expf(-a));
}

// ---------------- per-sample softmax + p@V + BN1 + residual ----------------
__global__ __launch_bounds__(256)
void attn_tail(const float* __restrict__ scorep, const short* __restrict__ Vbf,
               const float* __restrict__ cap, const int* __restrict__ lengths,
               const float* __restrict__ g1, const float* __restrict__ b1,
               const float* __restrict__ m1, const float* __restrict__ v1,
               float* __restrict__ xga)
{
    __shared__ float sc[512], red[512];
    const int b = blockIdx.x;
    const int t = threadIdx.x;
    int r = lengths[b] - 1;
    if (r < 0) r = 0;
    if (r > 255) r = 255;
    const size_t base = ((size_t)b * 256 + r) * 512;

#pragma unroll
    for (int i = 0; i < 2; ++i) {
        const int o = t + i * 256;
        const int h = o >> 8, j = o & 255;
        const size_t si = ((size_t)(b * 2 + h) * 256 + j) * 2;
        sc[o] = floorf((scorep[si] + scorep[si + 1]) * 0.0625f);
    }
    __syncthreads();

    red[t] = sc[t]; red[t + 256] = sc[t + 256];
    __syncthreads();
    for (int s = 128; s > 0; s >>= 1) {
        if (t < s) {
            red[t] = fmaxf(red[t], red[t + s]);
            red[256 + t] = fmaxf(red[256 + t], red[256 + t + s]);
        }
        __syncthreads();
    }
    const float mx0 = red[0], mx1 = red[256];
    __syncthreads();
    const float e0 = expf(sc[t] - mx0);
    const float e1 = expf(sc[t + 256] - mx1);
    sc[t] = e0; sc[t + 256] = e1;
    red[t] = e0; red[t + 256] = e1;
    __syncthreads();
    for (int s = 128; s > 0; s >>= 1) {
        if (t < s) { red[t] += red[t + s]; red[256 + t] += red[256 + t + s]; }
        __syncthreads();
    }
    const float inv0 = 1.f / red[0];
    const float inv1 = 1.f / red[256];

    // thread t handles cols {2t, 2t+1}, both in head h2 = t>>7
    const int h2 = t >> 7;
    float x0 = 0.f, x1 = 0.f;
    const float* ph = sc + h2 * 256;
    for (int j = 0; j < 256; ++j) {
        const int vv = ((const int*)(Vbf + ((size_t)(b * 256 + j)) * 512))[t];
        const float pj = ph[j];
        x0 += pj * bf2f((short)(vv & 0xffff));
        x1 += pj * bf2f((short)(vv >> 16));
    }
    const float inv = h2 ? inv1 : inv0;
    x0 *= inv; x1 *= inv;
    const int c0 = 2 * t, c1 = 2 * t + 1;
    const float s0 = g1[c0] / sqrtf(v1[c0] + 1e-5f);
    const float s1 = g1[c1] / sqrtf(v1[c1] + 1e-5f);
    xga[b * 512 + c0] = cap[base + c0] + (x0 - m1[c0]) * s0 + b1[c0];
    xga[b * 512 + c1] = cap[base + c1] + (x1 - m1[c1]) * s1 + b1[c1];
}

// ---------------- MLP strip GEMMs (weights read once) ----------------
__global__ __launch_bounds__(256)
void mlp1(const float* __restrict__ xga, const float* __restrict__ W,
          const float* __restrict__ bias, float* __restrict__ hid)
{
    __shared__ float xs[16 * 512];
    const int r0 = blockIdx.y * 16;
    const int c0 = blockIdx.x * 64;
    for (int i = threadIdx.x; i < 2048; i += 256)
        ((float4*)xs)[i] = ((const float4*)(xga + (size_t)r0 * 512))[i];
    __syncthreads();
    const int col = c0 + (threadIdx.x & 63);
    const int rg = (threadIdx.x >> 6) * 4;
    float acc[4] = {0.f, 0.f, 0.f, 0.f};
    const float4* w4 = (const float4*)(W + (size_t)col * 512);
    for (int k4 = 0; k4 < 128; ++k4) {
        float4 w = w4[k4];
#pragma unroll
        for (int rr = 0; rr < 4; ++rr) {
            float4 x = *(const float4*)&xs[(rg + rr) * 512 + k4 * 4];
            acc[rr] += w.x * x.x + w.y * x.y + w.z * x.z + w.w * x.w;
        }
    }
    const float bb = bias[col];
#pragma unroll
    for (int rr = 0; rr < 4; ++rr)
        hid[(size_t)(r0 + rg + rr) * 1024 + col] = fmaxf(acc[rr] + bb, 0.f);
}

__global__ __launch_bounds__(256)
void mlp2(const float* __restrict__ hid, const float* __restrict__ W,
          const float* __restrict__ bias, const float* __restrict__ xga,
          float* __restrict__ tex)
{
    __shared__ float xs[16 * 1024];
    const int r0 = blockIdx.y * 16;
    const int c0 = blockIdx.x * 64;
    for (int i = threadIdx.x; i < 4096; i += 256)
        ((float4*)xs)[i] = ((const float4*)(hid + (size_t)r0 * 1024))[i];
    __syncthreads();
    const int col = c0 + (threadIdx.x & 63);
    const int rg = (threadIdx.x >> 6) * 4;
    float acc[4] = {0.f, 0.f, 0.f, 0.f};
    const float4* w4 = (const float4*)(W + (size_t)col * 1024);
    for (int k4 = 0; k4 < 256; ++k4) {
        float4 w = w4[k4];
#pragma unroll
        for (int rr = 0; rr < 4; ++rr) {
            float4 x = *(const float4*)&xs[(rg + rr) * 1024 + k4 * 4];
            acc[rr] += w.x * x.x + w.y * x.y + w.z * x.z + w.w * x.w;
        }
    }
    const float bb = bias[col];
#pragma unroll
    for (int rr = 0; rr < 4; ++rr) {
        const int row = r0 + rg + rr;
        tex[(size_t)row * 512 + col] = acc[rr] + bb + xga[(size_t)row * 512 + col];
    }
}

__global__ __launch_bounds__(256)
void norm_out(const float* __restrict__ tex, float* __restrict__ out)
{
    __shared__ float red[256];
    const int b = blockIdx.x;
    const int t = threadIdx.x;
    const float a = tex[b * 512 + t];
    const float c = tex[b * 512 + 256 + t];
    red[t] = a * a + c * c;
    __syncthreads();
    for (int s = 128; s > 0; s >>= 1) {
        if (t < s) red[t] += red[t + s];
        __syncthreads();
    }
    const float inv = 1.f / (sqrtf(red[0]) + 1e-8f);
    out[b * 512 + t] = a * inv;
    out[b * 512 + 256 + t] = c * inv;
}

extern "C" void kernel_launch(void* const* d_in, const int* in_sizes, int n_in,
                              void* d_out, int out_size, void* d_ws, size_t ws_size,
                              hipStream_t stream)
{
    const float* cap = (const float*)d_in[0];
    const int* lengths = (const int*)d_in[1];
    const float* Wq  = (const float*)d_in[2];
    const float* Wk  = (const float*)d_in[3];
    const float* Wv  = (const float*)d_in[4];
    const float* bq  = (const float*)d_in[5];
    const float* bk  = (const float*)d_in[6];
    const float* bv  = (const float*)d_in[7];
    const float* Wfq = (const float*)d_in[8];
    const float* bfq = (const float*)d_in[9];
    const float* Wfk = (const float*)d_in[10];
    const float* bfk = (const float*)d_in[11];
    const float* Wfg = (const float*)d_in[12];
    const float* bfg = (const float*)d_in[13];
    const float* g1  = (const float*)d_in[14];
    const float* b1  = (const float*)d_in[15];
    const float* m1  = (const float*)d_in[16];
    const float* v1  = (const float*)d_in[17];
    const float* Wm1 = (const float*)d_in[30];
    const float* bm1 = (const float*)d_in[31];
    const float* Wm2 = (const float*)d_in[32];
    const float* bm2 = (const float*)d_in[33];
    float* out = (float*)d_out;

    char* w = (char*)d_ws;
    const size_t MB = 1024 * 1024;
    short* capHi = (short*)(w);                // 32MB  -> Ghi after V gemm
    short* capLo = (short*)(w + 32 * MB);      // 32MB  -> Glo
    short* QKhi  = (short*)(w + 64 * MB);      // 64MB  [32768,1024]: cols 0-511 Q, 512-1023 K
    short* QKlo  = (short*)(w + 128 * MB);     // 64MB
    short* Vbf   = (short*)(w + 192 * MB);     // 32MB
    char* wp = w + 224 * MB;
    short* WqkHi = (short*)wp; wp += 1048576 * 2;  // [1024,512]
    short* WqkLo = (short*)wp; wp += 1048576 * 2;
    short* WvHi  = (short*)wp; wp += 524288;
    short* WvLo  = (short*)wp; wp += 524288;
    short* WfqHi = (short*)wp; wp += 131072;
    short* WfqLo = (short*)wp; wp += 131072;
    short* WfkHi = (short*)wp; wp += 131072;
    short* WfkLo = (short*)wp; wp += 131072;
    short* Wfg2Hi = (short*)wp; wp += 131072;
    short* Wfg2Lo = (short*)wp; wp += 131072;
    float* qg     = (float*)wp; wp += 262144;
    float* scorep = (float*)wp; wp += 524288;   // [128][2][256][2]
    float* xga    = (float*)wp; wp += 262144;
    float* hid    = (float*)wp; wp += 524288;
    float* tex    = (float*)wp; wp += 262144;
    short* Ghi = capHi;
    short* Glo = capLo;

    // 1. split conversions (Wq -> rows 0-511 of Wqk, Wk -> rows 512-1023)
    SplitArgs sa;
    sa.src[0] = cap;  sa.hi[0] = capHi;            sa.lo[0] = capLo;            sa.n4[0] = 4194304;
    sa.src[1] = Wq;   sa.hi[1] = WqkHi;            sa.lo[1] = WqkLo;            sa.n4[1] = 65536;
    sa.src[2] = Wk;   sa.hi[2] = WqkHi + 262144;   sa.lo[2] = WqkLo + 262144;   sa.n4[2] = 65536;
    sa.src[3] = Wv;   sa.hi[3] = WvHi;             sa.lo[3] = WvLo;             sa.n4[3] = 65536;
    sa.src[4] = Wfq;  sa.hi[4] = WfqHi;            sa.lo[4] = WfqLo;            sa.n4[4] = 16384;
    sa.src[5] = Wfk;  sa.hi[5] = WfkHi;            sa.lo[5] = WfkLo;            sa.n4[5] = 16384;
    sa.src[6] = Wfg + 65536; sa.hi[6] = Wfg2Hi;    sa.lo[6] = Wfg2Lo;           sa.n4[6] = 16384;
    split_multi<<<dim3(4096, 7), 256, 0, stream>>>(sa);

    // 2. QK fused: [32768,512] x [1024,512]^T -> split [32768,1024]
    gemm_mfma<1, 3><<<dim3(8, 256, 1), 256, 0, stream>>>(
        capHi, capLo, 512, WqkHi, WqkLo, 512, bq, bk,
        nullptr, nullptr, 0, nullptr, nullptr,
        nullptr, nullptr, 0, 0, nullptr, nullptr,
        QKhi, QKlo, 1024, 512, 0, 0);

    // 3. V: plain bf16
    gemm_mfma<2, 1><<<dim3(4, 256, 1), 256, 0, stream>>>(
        capHi, nullptr, 512, WvHi, nullptr, 512, bv, nullptr,
        nullptr, nullptr, 0, nullptr, nullptr,
        nullptr, nullptr, 0, 0, nullptr, nullptr,
        Vbf, nullptr, 512, 512, 0, 0);

    // 4. G = (Q_h Wfq^T + bfq) * (K_h Wfk^T + bfk)  -> overwrites cap splits
    gemm_mfma<3, 3><<<dim3(2, 256, 2), 256, 0, stream>>>(
        QKhi, QKlo, 1024, WfqHi, WfqLo, 256, bfq, bfk,
        QKhi + 512, QKlo + 512, 256, WfkHi, WfkLo,
        nullptr, nullptr, 0, 0, nullptr, nullptr,
        Ghi, Glo, 512, 256, 256, 256);

    // 5. qg at gathered rows
    qg_kernel<<<dim3(256), 256, 0, stream>>>(QKhi, QKlo, Ghi, Glo, Wfg, bfg, lengths, qg);

    // 6. kg gemm with fused score partials (kg never materialized)
    gemm_mfma<4, 3><<<dim3(2, 256, 2), 256, 0, stream>>>(
        Ghi, Glo, 512, Wfg2Hi, Wfg2Lo, 256, bfg + 256, nullptr,
        nullptr, nullptr, 0, nullptr, nullptr,
        QKhi + 512, QKlo + 512, 1024, 256, qg, scorep,
        nullptr, nullptr, 0, 256, 256, 0);

    // 7-10. softmax+pV tail, MLP, norm
    attn_tail<<<dim3(128), 256, 0, stream>>>(scorep, Vbf, cap, lengths, g1, b1, m1, v1, xga);
    mlp1<<<dim3(16, 8), 256, 0, stream>>>(xga, Wm1, bm1, hid);
    mlp2<<<dim3(8, 8), 256, 0, stream>>>(hid, Wm2, bm2, xga, tex);
    norm_out<<<dim3(128), 256, 0, stream>>>(tex, out);
}